// Round 3
// baseline (3304.491 us; speedup 1.0000x reference)
//
#include <hip/hip_runtime.h>

// EntailmentSelfAttention: N=16, L=256, S=2, H=16, D=64, E=1024
//
// Pipeline (2 kernels):
//   K1 k_attn : FULLY FUSED proj(Q/K/V) + energy + softmax(axis=q) + PV
//               per (n,h,s) slice. Projections are computed in-kernel from
//               the raw input tensors (d_in) — the kP/qP/vP workspace
//               round-trip is gone. Rounds 0-2 showed the attention core
//               pinned at ~1200us with 3.6-6.7 GB of TCC traffic (20-80x
//               nominal) whenever operands came from d_ws; this tests and
//               removes that dependency. X is written in permuted layout
//               e' = hr*128 + s*64 + d (contiguous float4 stores; the old
//               stride-2 scatter had 80x write amplification).
//   K2 k_wo   : out = X @ Wo'^T + bo, where Wo columns are read through the
//               inverse permutation e = hr*128 + 2d + s.
//
// ws layout: X only: 8,388,608 f32 = 32 MiB at offset 0.
//
// k_attn LDS map (floats, total 38784 = 155,136 B, 1 block/CU):
//   Qs   @ 0      [256][68] = 17408   projected Q tile
//   WkS  @ 17408  [64][68]  =  4352   Wk resident
//   WvS  @ 21760  [64][68]  =  4352   Wv resident
//   Ks   @ 26112  [32][68]  =  2176   projected K chunk (Wq transient here)
//   vs   @ 28288  [32][68]  =  2176   projected V chunk
//   atts @ 30464  [32][260] =  8320   scores; raw-row staging scratch

#define QS_OFF   0
#define WK_OFF   17408
#define WV_OFF   21760
#define KS_OFF   26112
#define VS_OFF   28288
#define ATT_OFF  30464
#define RSK_OFF  ATT_OFF           // raw K rows (32x68)
#define RSV_OFF  (ATT_OFF + 2176)  // raw V rows (32x68)
#define WQ_OFF   KS_OFF            // Wq lives in Ks+vs during prologue

__global__ __launch_bounds__(512) void k_attn(
    const float* __restrict__ Av, const float* __restrict__ Ak,
    const float* __restrict__ Aq, const float* __restrict__ Wv,
    const float* __restrict__ Wk, const float* __restrict__ Wq,
    const int* __restrict__ mask, float* __restrict__ X)
{
    __shared__ float sm[38784];
    const int nhs = blockIdx.x;
    const int n = nhs >> 5, h = (nhs >> 1) & 15, s = nhs & 1;
    const int tid = threadIdx.x;
    // raw row for (l): A + n*524288 + l*2048 + s*1024 + h*64 + d
    const long rbase = (long)n * 524288 + s * 1024 + h * 64;

    // ---- stage Wk, Wv (resident) and Wq (transient) : [e][d] -> [64][68]
#pragma unroll
    for (int w = 0; w < 2; ++w) {
        int idx = w * 512 + tid;           // float4 index over 1024
        int r = idx >> 4, c = (idx & 15) * 4;
        *(float4*)&sm[WK_OFF + r * 68 + c] = *(const float4*)(Wk + r * 64 + c);
        *(float4*)&sm[WV_OFF + r * 68 + c] = *(const float4*)(Wv + r * 64 + c);
        *(float4*)&sm[WQ_OFF + r * 68 + c] = *(const float4*)(Wq + r * 64 + c);
    }

    const int sr = tid >> 4, sc = (tid & 15) * 4;  // 32x64 staging map
    const int pr = tid >> 4;                       // projection out row
    const int pe = tid & 15;                       // projection e base

    // ---- project Q into Qs, 8 sub-chunks of 32 rows
    for (int qc = 0; qc < 8; ++qc) {
        __syncthreads();  // W staged (qc=0) / prev projection reads done
        *(float4*)&sm[RSK_OFF + sr * 68 + sc] =
            *(const float4*)(Aq + rbase + (long)(qc * 32 + sr) * 2048 + sc);
        __syncthreads();
        float a0 = 0.f, a1 = 0.f, a2 = 0.f, a3 = 0.f;
#pragma unroll
        for (int k = 0; k < 64; k += 4) {
            float4 rv = *(const float4*)&sm[RSK_OFF + pr * 68 + k];
            float4 w0 = *(const float4*)&sm[WQ_OFF + (pe +  0) * 68 + k];
            float4 w1 = *(const float4*)&sm[WQ_OFF + (pe + 16) * 68 + k];
            float4 w2 = *(const float4*)&sm[WQ_OFF + (pe + 32) * 68 + k];
            float4 w3 = *(const float4*)&sm[WQ_OFF + (pe + 48) * 68 + k];
            a0 += rv.x * w0.x + rv.y * w0.y + rv.z * w0.z + rv.w * w0.w;
            a1 += rv.x * w1.x + rv.y * w1.y + rv.z * w1.z + rv.w * w1.w;
            a2 += rv.x * w2.x + rv.y * w2.y + rv.z * w2.z + rv.w * w2.w;
            a3 += rv.x * w3.x + rv.y * w3.y + rv.z * w3.z + rv.w * w3.w;
        }
        const int qrow = qc * 32 + pr;
        sm[QS_OFF + qrow * 68 + pe +  0] = a0;
        sm[QS_OFF + qrow * 68 + pe + 16] = a1;
        sm[QS_OFF + qrow * 68 + pe + 32] = a2;
        sm[QS_OFF + qrow * 68 + pe + 48] = a3;
    }

    // GEMM map: l = gty + 8*i, q = gtx + 64*j
    const int gty = tid >> 6, gtx = tid & 63;
    // mask depends only on q: mask[n, h>>3, 0, (h&7)*32 + s*16 + (q>>4)]
    const int mrow = n * 524288 + (h >> 3) * 262144 + (h & 7) * 32 + s * 16;
    float mbit[4];
#pragma unroll
    for (int j = 0; j < 4; ++j) {
        int q = gtx + 64 * j;
        mbit[j] = (mask[mrow + (q >> 4)] != 0) ? 1.f : 0.f;
    }

    // PV map: q = pty*4 + i, d = ptx*8 + j
    const int pty = tid >> 3, ptx = tid & 7;
    float acc[4][8];
#pragma unroll
    for (int i = 0; i < 4; ++i)
#pragma unroll
        for (int j = 0; j < 8; ++j) acc[i][j] = 0.f;

    const int lane = tid & 63;
    const float scale = 0.03125f;  // 1/sqrt(1024)

    for (int lc0 = 0; lc0 < 256; lc0 += 32) {
        __syncthreads();  // prev PV done; Q projection done (iter 0)
        *(float4*)&sm[RSK_OFF + sr * 68 + sc] =
            *(const float4*)(Ak + rbase + (long)(lc0 + sr) * 2048 + sc);
        *(float4*)&sm[RSV_OFF + sr * 68 + sc] =
            *(const float4*)(Av + rbase + (long)(lc0 + sr) * 2048 + sc);
        __syncthreads();

        // ---- project K and V chunk -> Ks, vs
        {
            float k0 = 0.f, k1 = 0.f, k2 = 0.f, k3 = 0.f;
            float v0 = 0.f, v1 = 0.f, v2 = 0.f, v3 = 0.f;
#pragma unroll
            for (int k = 0; k < 64; k += 4) {
                float4 rk = *(const float4*)&sm[RSK_OFF + pr * 68 + k];
                float4 rv = *(const float4*)&sm[RSV_OFF + pr * 68 + k];
                float4 wk0 = *(const float4*)&sm[WK_OFF + (pe +  0) * 68 + k];
                float4 wk1 = *(const float4*)&sm[WK_OFF + (pe + 16) * 68 + k];
                float4 wk2 = *(const float4*)&sm[WK_OFF + (pe + 32) * 68 + k];
                float4 wk3 = *(const float4*)&sm[WK_OFF + (pe + 48) * 68 + k];
                k0 += rk.x * wk0.x + rk.y * wk0.y + rk.z * wk0.z + rk.w * wk0.w;
                k1 += rk.x * wk1.x + rk.y * wk1.y + rk.z * wk1.z + rk.w * wk1.w;
                k2 += rk.x * wk2.x + rk.y * wk2.y + rk.z * wk2.z + rk.w * wk2.w;
                k3 += rk.x * wk3.x + rk.y * wk3.y + rk.z * wk3.z + rk.w * wk3.w;
                float4 wv0 = *(const float4*)&sm[WV_OFF + (pe +  0) * 68 + k];
                float4 wv1 = *(const float4*)&sm[WV_OFF + (pe + 16) * 68 + k];
                float4 wv2 = *(const float4*)&sm[WV_OFF + (pe + 32) * 68 + k];
                float4 wv3 = *(const float4*)&sm[WV_OFF + (pe + 48) * 68 + k];
                v0 += rv.x * wv0.x + rv.y * wv0.y + rv.z * wv0.z + rv.w * wv0.w;
                v1 += rv.x * wv1.x + rv.y * wv1.y + rv.z * wv1.z + rv.w * wv1.w;
                v2 += rv.x * wv2.x + rv.y * wv2.y + rv.z * wv2.z + rv.w * wv2.w;
                v3 += rv.x * wv3.x + rv.y * wv3.y + rv.z * wv3.z + rv.w * wv3.w;
            }
            sm[KS_OFF + pr * 68 + pe +  0] = k0;
            sm[KS_OFF + pr * 68 + pe + 16] = k1;
            sm[KS_OFF + pr * 68 + pe + 32] = k2;
            sm[KS_OFF + pr * 68 + pe + 48] = k3;
            sm[VS_OFF + pr * 68 + pe +  0] = v0;
            sm[VS_OFF + pr * 68 + pe + 16] = v1;
            sm[VS_OFF + pr * 68 + pe + 32] = v2;
            sm[VS_OFF + pr * 68 + pe + 48] = v3;
        }
        __syncthreads();  // Ks/vs ready; raw staging (atts region) dead

        // ---- S-chunk GEMM (32 l x 256 q x 64 k), masked scale -> atts
        {
            float sacc[4][4];
#pragma unroll
            for (int i = 0; i < 4; ++i)
#pragma unroll
                for (int j = 0; j < 4; ++j) sacc[i][j] = 0.f;
#pragma unroll
            for (int kk = 0; kk < 64; kk += 4) {
                float4 a[4], bb[4];
#pragma unroll
                for (int i = 0; i < 4; ++i)
                    a[i] = *(const float4*)&sm[KS_OFF + (gty + 8 * i) * 68 + kk];
#pragma unroll
                for (int j = 0; j < 4; ++j)
                    bb[j] = *(const float4*)&sm[QS_OFF + (gtx + 64 * j) * 68 + kk];
#pragma unroll
                for (int i = 0; i < 4; ++i)
#pragma unroll
                    for (int j = 0; j < 4; ++j) {
                        sacc[i][j] += a[i].x * bb[j].x;
                        sacc[i][j] += a[i].y * bb[j].y;
                        sacc[i][j] += a[i].z * bb[j].z;
                        sacc[i][j] += a[i].w * bb[j].w;
                    }
            }
#pragma unroll
            for (int i = 0; i < 4; ++i)
#pragma unroll
                for (int j = 0; j < 4; ++j)
                    sm[ATT_OFF + (gty + 8 * i) * 260 + gtx + 64 * j] =
                        (mbit[j] != 0.f) ? sacc[i][j] * scale : -3.125e18f;
        }
        __syncthreads();

        // ---- row softmax over q: wave per 4 rows
#pragma unroll
        for (int rr = 0; rr < 4; ++rr) {
            const int r = gty * 4 + rr;
            float4 v = *(const float4*)&sm[ATT_OFF + r * 260 + lane * 4];
            float m = fmaxf(fmaxf(v.x, v.y), fmaxf(v.z, v.w));
#pragma unroll
            for (int off = 1; off < 64; off <<= 1)
                m = fmaxf(m, __shfl_xor(m, off));
            float4 e;
            e.x = expf(v.x - m);
            e.y = expf(v.y - m);
            e.z = expf(v.z - m);
            e.w = expf(v.w - m);
            float zs = e.x + e.y + e.z + e.w;
#pragma unroll
            for (int off = 1; off < 64; off <<= 1) zs += __shfl_xor(zs, off);
            const float iz = 1.0f / zs;
            e.x *= iz; e.y *= iz; e.z *= iz; e.w *= iz;
            *(float4*)&sm[ATT_OFF + r * 260 + lane * 4] = e;
        }
        __syncthreads();

        // ---- PV: acc[q][d] += atts[lc][q] * vs[lc][d]
#pragma unroll
        for (int lc = 0; lc < 32; ++lc) {
            float4 a0 = *(const float4*)&sm[ATT_OFF + lc * 260 + pty * 4];
            float4 v0 = *(const float4*)&sm[VS_OFF + lc * 68 + ptx * 8];
            float4 v1 = *(const float4*)&sm[VS_OFF + lc * 68 + ptx * 8 + 4];
            float av[4] = {a0.x, a0.y, a0.z, a0.w};
            float vv[8] = {v0.x, v0.y, v0.z, v0.w, v1.x, v1.y, v1.z, v1.w};
#pragma unroll
            for (int i = 0; i < 4; ++i)
#pragma unroll
                for (int j = 0; j < 8; ++j) acc[i][j] += av[i] * vv[j];
        }
    }

    // ---- write X in PERMUTED layout: X[(n,q,s2)][hr*128 + s*64 + d]
    // contiguous float4 stores (old layout e=hr*128+2d+s scattered 4B stores)
    const int s2 = h >> 3, hr = h & 7;
#pragma unroll
    for (int i = 0; i < 4; ++i) {
        int q = pty * 4 + i;
        long xb = ((long)((n * 256 + q) * 2 + s2)) * 1024 + hr * 128 + s * 64 +
                  ptx * 8;
        float4 o0 = {acc[i][0], acc[i][1], acc[i][2], acc[i][3]};
        float4 o1 = {acc[i][4], acc[i][5], acc[i][6], acc[i][7]};
        *(float4*)&X[xb] = o0;
        *(float4*)&X[xb + 4] = o1;
    }
}

// out = X @ Wo'^T + bo. X columns are permuted (e' = hr*128 + s*64 + d);
// Wo columns are read through the inverse permutation e = hr*128 + 2d + s.
__global__ __launch_bounds__(256) void k_wo(
    const float* __restrict__ X, const float* __restrict__ Wo,
    const float* __restrict__ bo, float* __restrict__ out)
{
    __shared__ float Xs[128][36];
    __shared__ float Ws[128][36];
    const int b = blockIdx.x;
    const int by = b >> 3, bx = b & 7;
    const int r0 = by * 128, f0 = bx * 128;
    const int tid = threadIdx.x, ty = tid >> 4, tx = tid & 15;

    float acc[8][8];
#pragma unroll
    for (int i = 0; i < 8; ++i)
#pragma unroll
        for (int j = 0; j < 8; ++j) acc[i][j] = 0.f;

    for (int k0 = 0; k0 < 1024; k0 += 32) {
        const int hr = k0 >> 7;
        const int sp = (k0 >> 6) & 1;
        const int d0 = k0 & 63;  // 0 or 32
        __syncthreads();
#pragma unroll
        for (int w = 0; w < 4; ++w) {
            int idx = w * 1024 + tid * 4;
            int r = idx >> 5, c = idx & 31;
            *(float4*)&Xs[r][c] =
                *(const float4*)(X + (long)(r0 + r) * 1024 + k0 + c);
            const float* wrow = Wo + (long)(f0 + r) * 1024 + hr * 128 + sp;
#pragma unroll
            for (int u = 0; u < 4; ++u)
                Ws[r][c + u] = wrow[2 * (d0 + c + u)];
        }
        __syncthreads();
#pragma unroll
        for (int kk = 0; kk < 32; kk += 4) {
            float4 a[8], bb[8];
#pragma unroll
            for (int i = 0; i < 8; ++i)
                a[i] = *(const float4*)&Xs[ty + 16 * i][kk];
#pragma unroll
            for (int j = 0; j < 8; ++j)
                bb[j] = *(const float4*)&Ws[tx + 16 * j][kk];
#pragma unroll
            for (int i = 0; i < 8; ++i)
#pragma unroll
                for (int j = 0; j < 8; ++j) {
                    acc[i][j] += a[i].x * bb[j].x;
                    acc[i][j] += a[i].y * bb[j].y;
                    acc[i][j] += a[i].z * bb[j].z;
                    acc[i][j] += a[i].w * bb[j].w;
                }
        }
    }

#pragma unroll
    for (int i = 0; i < 8; ++i)
#pragma unroll
        for (int j = 0; j < 8; ++j) {
            int r = r0 + ty + 16 * i, f = f0 + tx + 16 * j;
            out[(long)r * 1024 + f] = acc[i][j] + bo[f];
        }
}

extern "C" void kernel_launch(void* const* d_in, const int* in_sizes, int n_in,
                              void* d_out, int out_size, void* d_ws,
                              size_t ws_size, hipStream_t stream)
{
    const float* vals = (const float*)d_in[0];
    const float* keys = (const float*)d_in[1];
    const float* qrys = (const float*)d_in[2];
    const int*   mask = (const int*)d_in[3];
    const float* Wv   = (const float*)d_in[4];
    const float* Wk   = (const float*)d_in[5];
    const float* Wq   = (const float*)d_in[6];
    const float* Wo   = (const float*)d_in[7];
    const float* bo   = (const float*)d_in[8];
    float* X   = (float*)d_ws;
    float* out = (float*)d_out;

    k_attn<<<512, 512, 0, stream>>>(vals, keys, qrys, Wv, Wk, Wq, mask, X);
    k_wo<<<512, 256, 0, stream>>>(X, Wo, bo, out);
}

// Round 4
// 1557.524 us; speedup vs baseline: 2.1216x; 2.1216x over previous
//
#include <hip/hip_runtime.h>

// EntailmentSelfAttention: N=16, L=256, S=2, H=16, D=64, E=1024
//
// Pipeline (3 kernels, r2 structure; this round changes ONLY the X path):
//   K1 k_proj : vP/kP/qP[n][h][s][l][d] = row(values/keys/query) @ W^T
//   K2 k_attn : fused energy+softmax(axis=q)+PV per (n,h,s) slice.
//               NEW: X stored as [nhs][q][d] -> each block writes ONE
//               CONTIGUOUS 64-KB slice (r2 wrote 4-B elements at stride 8B
//               across 8-KB-stride rows -> 80x write amplification; every
//               amplified kernel in r0-r3 had small segments at multi-KB
//               strides on some side; this is the first fully-contiguous-
//               both-sides attention core).
//   K3 k_wo   : out[r][f] = sum_e X'[r][e] Wo[f][e] + bo. X is gathered
//               from slices (128-B segs at 256-B stride, page-dense);
//               Wo columns via inverse permutation e = hr*128 + 2d + sp
//               using paired float4 loads (parity select, no scalar gather).
//
// ws layout (f32): vP @0, kP @8388608, qP @16777216, X @25165824 (134 MB).

__global__ __launch_bounds__(256) void k_proj(
    const float* __restrict__ Av, const float* __restrict__ Ak,
    const float* __restrict__ Aq, const float* __restrict__ Wv,
    const float* __restrict__ Wk, const float* __restrict__ Wq,
    float* __restrict__ vP, float* __restrict__ kP, float* __restrict__ qP)
{
    __shared__ float As[3][64][36];
    __shared__ float Ws[3][64][36];
    const int b = blockIdx.x;
    const int h = b & 15, s = (b >> 4) & 1, lblk = (b >> 5) & 3, n = b >> 7;
    const int l0 = lblk * 64;
    const float* Asrc[3] = {Av, Ak, Aq};
    const float* Wsrc[3] = {Wv, Wk, Wq};
    float* Pdst[3] = {vP, kP, qP};
    const int tid = threadIdx.x;
    const int ty = tid >> 4, tx = tid & 15;

    float acc[3][4][4];
#pragma unroll
    for (int m = 0; m < 3; ++m)
#pragma unroll
        for (int i = 0; i < 4; ++i)
#pragma unroll
            for (int j = 0; j < 4; ++j) acc[m][i][j] = 0.f;

    const long baseA = (long)n * 524288 + (long)l0 * 2048 + s * 1024 + h * 64;

#pragma unroll
    for (int k0 = 0; k0 < 64; k0 += 32) {
        __syncthreads();
#pragma unroll
        for (int m = 0; m < 3; ++m) {
#pragma unroll
            for (int w = 0; w < 2; ++w) {
                int idx = w * 1024 + tid * 4;
                int r = idx >> 5, c = idx & 31;
                *(float4*)&As[m][r][c] =
                    *(const float4*)(Asrc[m] + baseA + (long)r * 2048 + k0 + c);
                *(float4*)&Ws[m][r][c] =
                    *(const float4*)(Wsrc[m] + r * 64 + k0 + c);
            }
        }
        __syncthreads();
#pragma unroll
        for (int kk = 0; kk < 32; kk += 4) {
            float4 a[3][4], wb[3][4];
#pragma unroll
            for (int m = 0; m < 3; ++m)
#pragma unroll
                for (int i = 0; i < 4; ++i)
                    a[m][i] = *(const float4*)&As[m][ty + 16 * i][kk];
#pragma unroll
            for (int m = 0; m < 3; ++m)
#pragma unroll
                for (int j = 0; j < 4; ++j)
                    wb[m][j] = *(const float4*)&Ws[m][tx + 16 * j][kk];
#pragma unroll
            for (int m = 0; m < 3; ++m)
#pragma unroll
                for (int i = 0; i < 4; ++i)
#pragma unroll
                    for (int j = 0; j < 4; ++j) {
                        acc[m][i][j] += a[m][i].x * wb[m][j].x;
                        acc[m][i][j] += a[m][i].y * wb[m][j].y;
                        acc[m][i][j] += a[m][i].z * wb[m][j].z;
                        acc[m][i][j] += a[m][i].w * wb[m][j].w;
                    }
        }
    }

    // vP/kP/qP layout: [n][h][s][l][d]  (slice of 256x64 contiguous per nhs)
    const long pbase = ((long)((n * 16 + h) * 2 + s)) * 16384 + (long)l0 * 64;
#pragma unroll
    for (int m = 0; m < 3; ++m)
#pragma unroll
        for (int i = 0; i < 4; ++i)
#pragma unroll
            for (int j = 0; j < 4; ++j)
                Pdst[m][pbase + (ty + 16 * i) * 64 + tx + 16 * j] = acc[m][i][j];
}

// Fused attention per nhs slice. 512 threads (8 waves), ~118 KB LDS.
// Identical to r2 except the epilogue: X[nhs][q][d], contiguous 64-KB slice.
__global__ __launch_bounds__(512) void k_attn(
    const float* __restrict__ kP, const float* __restrict__ qP,
    const float* __restrict__ vP, const int* __restrict__ mask,
    float* __restrict__ X)
{
    __shared__ float Qs[256][68];    // 69,632 B
    __shared__ float Ks[32][68];     //  8,704 B
    __shared__ float vs[32][68];     //  8,704 B
    __shared__ float atts[32][260];  // 33,280 B

    const int nhs = blockIdx.x;
    const int n = nhs >> 5, h = (nhs >> 1) & 15, s = nhs & 1;
    const long slice = (long)nhs * 16384;
    const int tid = threadIdx.x;

    // ---- stage Q (256x64) once; covered by the first in-loop barrier
#pragma unroll
    for (int w = 0; w < 8; ++w) {
        int idx = w * 2048 + tid * 4;
        int r = idx >> 6, c = idx & 63;
        *(float4*)&Qs[r][c] = *(const float4*)(qP + slice + r * 64 + c);
    }

    // GEMM thread map: l = gty + 8*i (i<4), q = gtx + 64*j (j<4)
    const int gty = tid >> 6;   // == wave id -> Ks reads broadcast
    const int gtx = tid & 63;
    // mask depends only on q: mask[n, h>>3, 0, (h&7)*32 + s*16 + (q>>4)]
    const int mrow = n * 524288 + (h >> 3) * 262144 + (h & 7) * 32 + s * 16;
    float mbit[4];
#pragma unroll
    for (int j = 0; j < 4; ++j) {
        int q = gtx + 64 * j;
        mbit[j] = (mask[mrow + (q >> 4)] != 0) ? 1.f : 0.f;
    }

    // PV thread map: q = pty*4 + i (i<4), d = ptx*8 + j (j<8)
    const int pty = tid >> 3, ptx = tid & 7;
    float acc[4][8];
#pragma unroll
    for (int i = 0; i < 4; ++i)
#pragma unroll
        for (int j = 0; j < 8; ++j) acc[i][j] = 0.f;

    // staging map for K/V chunk: one float4/thread
    const int sr = tid >> 4, sc = (tid & 15) * 4;
    const int lane = tid & 63;

    const float scale = 0.03125f; // 1/sqrt(1024)

    for (int lc0 = 0; lc0 < 256; lc0 += 32) {
        __syncthreads();  // prev PV done reading Ks/vs/atts; Qs ready (iter 0)
        *(float4*)&Ks[sr][sc] =
            *(const float4*)(kP + slice + (lc0 + sr) * 64 + sc);
        *(float4*)&vs[sr][sc] =
            *(const float4*)(vP + slice + (lc0 + sr) * 64 + sc);
        __syncthreads();

        // ---- S-chunk GEMM (32 x 256 x 64)
        float sacc[4][4];
#pragma unroll
        for (int i = 0; i < 4; ++i)
#pragma unroll
            for (int j = 0; j < 4; ++j) sacc[i][j] = 0.f;
#pragma unroll
        for (int kk = 0; kk < 64; kk += 4) {
            float4 a[4], bb[4];
#pragma unroll
            for (int i = 0; i < 4; ++i)
                a[i] = *(const float4*)&Ks[gty + 8 * i][kk];
#pragma unroll
            for (int j = 0; j < 4; ++j)
                bb[j] = *(const float4*)&Qs[gtx + 64 * j][kk];
#pragma unroll
            for (int i = 0; i < 4; ++i)
#pragma unroll
                for (int j = 0; j < 4; ++j) {
                    sacc[i][j] += a[i].x * bb[j].x;
                    sacc[i][j] += a[i].y * bb[j].y;
                    sacc[i][j] += a[i].z * bb[j].z;
                    sacc[i][j] += a[i].w * bb[j].w;
                }
        }
        // masked scale, raw scores into LDS
#pragma unroll
        for (int i = 0; i < 4; ++i)
#pragma unroll
            for (int j = 0; j < 4; ++j)
                atts[gty + 8 * i][gtx + 64 * j] =
                    (mbit[j] != 0.f) ? sacc[i][j] * scale : -3.125e18f;
        __syncthreads();

        // ---- row softmax over q (axis 3 of reference): wave per 4 rows
#pragma unroll
        for (int rr = 0; rr < 4; ++rr) {
            const int r = gty * 4 + rr;
            float4 v = *(const float4*)&atts[r][lane * 4];
            float m = fmaxf(fmaxf(v.x, v.y), fmaxf(v.z, v.w));
#pragma unroll
            for (int off = 1; off < 64; off <<= 1)
                m = fmaxf(m, __shfl_xor(m, off));
            float4 e;
            e.x = expf(v.x - m);
            e.y = expf(v.y - m);
            e.z = expf(v.z - m);
            e.w = expf(v.w - m);
            float zs = e.x + e.y + e.z + e.w;
#pragma unroll
            for (int off = 1; off < 64; off <<= 1) zs += __shfl_xor(zs, off);
            const float iz = 1.0f / zs;
            e.x *= iz; e.y *= iz; e.z *= iz; e.w *= iz;
            *(float4*)&atts[r][lane * 4] = e;
        }
        __syncthreads();

        // ---- PV accumulate: acc[q][d] += atts[lc][q] * vs[lc][d]
#pragma unroll
        for (int lc = 0; lc < 32; ++lc) {
            float4 a0 = *(const float4*)&atts[lc][pty * 4];
            float4 v0 = *(const float4*)&vs[lc][ptx * 8];
            float4 v1 = *(const float4*)&vs[lc][ptx * 8 + 4];
            float av[4] = {a0.x, a0.y, a0.z, a0.w};
            float vv[8] = {v0.x, v0.y, v0.z, v0.w, v1.x, v1.y, v1.z, v1.w};
#pragma unroll
            for (int i = 0; i < 4; ++i)
#pragma unroll
                for (int j = 0; j < 8; ++j) acc[i][j] += av[i] * vv[j];
        }
    }

    // ---- write X[nhs][q][d]: one fully contiguous 64-KB slice per block
#pragma unroll
    for (int i = 0; i < 4; ++i) {
        int q = pty * 4 + i;
        long xb = slice + q * 64 + ptx * 8;
        float4 o0 = {acc[i][0], acc[i][1], acc[i][2], acc[i][3]};
        float4 o1 = {acc[i][4], acc[i][5], acc[i][6], acc[i][7]};
        *(float4*)&X[xb] = o0;
        *(float4*)&X[xb + 4] = o1;
    }
}

// out[r][f] = sum_e Xrow[r][e] Wo[f][e] + bo[f], r = (n*256+q)*2+s2.
// Xrow[r][e] with e=(hr,d,sp) lives at X[((n*16+(s2*8+hr))*2+sp)][q][d].
// Per k-slab of 32: hr,sp fixed, d in [d0,d0+32) -> slice-local float4 loads.
// Wo gathered via paired float4 + parity select (e = hr*128 + 2d + sp).
__global__ __launch_bounds__(256) void k_wo(
    const float* __restrict__ X, const float* __restrict__ Wo,
    const float* __restrict__ bo, float* __restrict__ out)
{
    __shared__ float Xs[128][36];
    __shared__ float Ws[128][36];
    const int b = blockIdx.x;
    const int by = b >> 3, bx = b & 7;
    const int r0 = by * 128, f0 = bx * 128;
    const int tid = threadIdx.x, ty = tid >> 4, tx = tid & 15;

    float acc[8][8];
#pragma unroll
    for (int i = 0; i < 8; ++i)
#pragma unroll
        for (int j = 0; j < 8; ++j) acc[i][j] = 0.f;

    for (int k0 = 0; k0 < 1024; k0 += 32) {
        const int hr = k0 >> 7;         // head-in-group 0..7
        const int sp = (k0 >> 6) & 1;   // s parity of e
        const int d0 = k0 & 63;         // 0 or 32
        __syncthreads();
#pragma unroll
        for (int w = 0; w < 4; ++w) {
            int idx = w * 1024 + tid * 4;
            int r = idx >> 5, c = idx & 31;
            // X gather: row R=(r0+r) -> n,q,s2; slice nhs=(n*16+s2*8+hr)*2+sp
            int R = r0 + r;
            int n = R >> 9, q = (R >> 1) & 255, s2 = R & 1;
            long xoff = ((long)((n * 16 + (s2 * 8 + hr)) * 2 + sp)) * 16384 +
                        q * 64 + d0 + c;
            *(float4*)&Xs[r][c] = *(const float4*)(X + xoff);
            // Wo gather: e = hr*128 + 2*(d0+c..c+3) + sp via 2 float4 loads
            const float* wrow = Wo + (long)(f0 + r) * 1024 + hr * 128 +
                                2 * (d0 + c);
            float4 pA = *(const float4*)(wrow);
            float4 pB = *(const float4*)(wrow + 4);
            if (sp == 0) {
                Ws[r][c]     = pA.x; Ws[r][c + 1] = pA.z;
                Ws[r][c + 2] = pB.x; Ws[r][c + 3] = pB.z;
            } else {
                Ws[r][c]     = pA.y; Ws[r][c + 1] = pA.w;
                Ws[r][c + 2] = pB.y; Ws[r][c + 3] = pB.w;
            }
        }
        __syncthreads();
#pragma unroll
        for (int kk = 0; kk < 32; kk += 4) {
            float4 a[8], bb[8];
#pragma unroll
            for (int i = 0; i < 8; ++i)
                a[i] = *(const float4*)&Xs[ty + 16 * i][kk];
#pragma unroll
            for (int j = 0; j < 8; ++j)
                bb[j] = *(const float4*)&Ws[tx + 16 * j][kk];
#pragma unroll
            for (int i = 0; i < 8; ++i)
#pragma unroll
                for (int j = 0; j < 8; ++j) {
                    acc[i][j] += a[i].x * bb[j].x;
                    acc[i][j] += a[i].y * bb[j].y;
                    acc[i][j] += a[i].z * bb[j].z;
                    acc[i][j] += a[i].w * bb[j].w;
                }
        }
    }

#pragma unroll
    for (int i = 0; i < 8; ++i)
#pragma unroll
        for (int j = 0; j < 8; ++j) {
            int r = r0 + ty + 16 * i, f = f0 + tx + 16 * j;
            out[(long)r * 1024 + f] = acc[i][j] + bo[f];
        }
}

extern "C" void kernel_launch(void* const* d_in, const int* in_sizes, int n_in,
                              void* d_out, int out_size, void* d_ws,
                              size_t ws_size, hipStream_t stream)
{
    const float* vals = (const float*)d_in[0];
    const float* keys = (const float*)d_in[1];
    const float* qrys = (const float*)d_in[2];
    const int*   mask = (const int*)d_in[3];
    const float* Wv   = (const float*)d_in[4];
    const float* Wk   = (const float*)d_in[5];
    const float* Wq   = (const float*)d_in[6];
    const float* Wo   = (const float*)d_in[7];
    const float* bo   = (const float*)d_in[8];
    float* ws  = (float*)d_ws;
    float* vP  = ws;
    float* kP  = ws + 8388608;
    float* qP  = ws + 16777216;
    float* X   = ws + 25165824;
    float* out = (float*)d_out;

    k_proj<<<2048, 256, 0, stream>>>(vals, keys, qrys, Wv, Wk, Wq, vP, kP, qP);
    k_attn<<<512, 512, 0, stream>>>(kP, qP, vP, mask, X);
    k_wo<<<512, 256, 0, stream>>>(X, Wo, bo, out);
}